// Round 1
// baseline (1684.354 us; speedup 1.0000x reference)
//
#include <hip/hip_runtime.h>

#define N_NODES 100000
#define E_EDGES 3200000
#define ET_EDGES (E_EDGES + N_NODES)   // edges incl. self-loops
#define IN_F 512
#define H_F 32
#define OUT_F 64
#define BN_EPS 1e-5f

// ---------------- degree / norm ----------------
__global__ void k_deg(const int* __restrict__ dst, unsigned* __restrict__ deg) {
    int i = blockIdx.x * blockDim.x + threadIdx.x;
    if (i < E_EDGES) atomicAdd(&deg[dst[i]], 1u);
}

__global__ void k_dinv(const unsigned* __restrict__ deg, float* __restrict__ dinv) {
    int i = blockIdx.x * blockDim.x + threadIdx.x;
    if (i < N_NODES) dinv[i] = rsqrtf((float)deg[i] + 1.0f);  // +1 self-loop
}

// ---------------- BN fold ----------------
__global__ void k_scales(const float* __restrict__ gamma, const float* __restrict__ beta,
                         const float* __restrict__ rm, const float* __restrict__ rv,
                         const float* __restrict__ b1,
                         float* __restrict__ scale, float* __restrict__ shift) {
    int k = threadIdx.x;
    if (k < H_F) {
        float s = gamma[k] * rsqrtf(rv[k] + BN_EPS);
        scale[k] = s;
        shift[k] = (b1[k] - rm[k]) * s + beta[k];
    }
}

// ---------------- GEMM1: xw = x @ W1  ([N,512] x [512,32]) ----------------
__global__ __launch_bounds__(256) void k_gemm1(const float* __restrict__ x,
                                               const float* __restrict__ W1,
                                               float* __restrict__ xw) {
    __shared__ float w[IN_F * H_F];  // 64 KB
    for (int i = threadIdx.x; i < IN_F * H_F; i += 256) w[i] = W1[i];
    __syncthreads();
    int c = threadIdx.x & 31;
    int r = threadIdx.x >> 5;        // 8 rows per block
    int row = blockIdx.x * 8 + r;
    if (row >= N_NODES) return;
    const float* xr = x + (long long)row * IN_F;
    float acc = 0.f;
#pragma unroll 8
    for (int k = 0; k < IN_F; ++k)
        acc = fmaf(xr[k], w[k * H_F + c], acc);
    xw[row * H_F + c] = acc;
}

// ---------------- scatter1: agg1 += xw[src]*norm  (width 32) ----------------
__global__ __launch_bounds__(256) void k_scatter1(const int* __restrict__ src,
                                                  const int* __restrict__ dst,
                                                  const float* __restrict__ dinv,
                                                  const float* __restrict__ xw,
                                                  float* __restrict__ agg) {
    int t = blockIdx.x * blockDim.x + threadIdx.x;
    int c = t & 31;
    int e = t >> 5;
    if (e >= ET_EDGES) return;
    int s, d;
    if (e < E_EDGES) { s = src[e]; d = dst[e]; }
    else             { s = e - E_EDGES; d = s; }
    float nrm = dinv[s] * dinv[d];
    atomicAdd(&agg[d * H_F + c], xw[s * H_F + c] * nrm);
}

// ---------------- GEMM2 (+BN+ReLU fused on input): hw = relu(bn(agg1)) @ W2 ----------------
__global__ __launch_bounds__(256) void k_gemm2(const float* __restrict__ agg,
                                               const float* __restrict__ W2,
                                               const float* __restrict__ scale,
                                               const float* __restrict__ shift,
                                               float* __restrict__ hw) {
    __shared__ float w[H_F * OUT_F];  // 8 KB
    __shared__ float sc[H_F], sh[H_F];
    for (int i = threadIdx.x; i < H_F * OUT_F; i += 256) w[i] = W2[i];
    if (threadIdx.x < H_F) {
        sc[threadIdx.x] = scale[threadIdx.x];
        sh[threadIdx.x] = shift[threadIdx.x];
    }
    __syncthreads();
    int c = threadIdx.x & 63;
    int r = threadIdx.x >> 6;        // 4 rows per block
    int row = blockIdx.x * 4 + r;
    if (row >= N_NODES) return;
    const float* ar = agg + row * H_F;
    float acc = 0.f;
#pragma unroll
    for (int k = 0; k < H_F; ++k) {
        float h = fmaxf(fmaf(ar[k], sc[k], sh[k]), 0.f);
        acc = fmaf(h, w[k * OUT_F + c], acc);
    }
    hw[row * OUT_F + c] = acc;
}

// ---------------- out init: out = b2 (broadcast) ----------------
__global__ void k_init_out(const float* __restrict__ b2, float* __restrict__ out) {
    int i = blockIdx.x * blockDim.x + threadIdx.x;
    if (i < N_NODES * OUT_F) out[i] = b2[i & (OUT_F - 1)];
}

// ---------------- scatter2: out += hw[src]*norm  (width 64) ----------------
__global__ __launch_bounds__(256) void k_scatter2(const int* __restrict__ src,
                                                  const int* __restrict__ dst,
                                                  const float* __restrict__ dinv,
                                                  const float* __restrict__ hw,
                                                  float* __restrict__ out) {
    int t = blockIdx.x * blockDim.x + threadIdx.x;
    int c = t & 63;
    int e = t >> 6;
    if (e >= ET_EDGES) return;
    int s, d;
    if (e < E_EDGES) { s = src[e]; d = dst[e]; }
    else             { s = e - E_EDGES; d = s; }
    float nrm = dinv[s] * dinv[d];
    atomicAdd(&out[d * OUT_F + c], hw[s * OUT_F + c] * nrm);
}

extern "C" void kernel_launch(void* const* d_in, const int* in_sizes, int n_in,
                              void* d_out, int out_size, void* d_ws, size_t ws_size,
                              hipStream_t stream) {
    const float* x     = (const float*)d_in[0];
    const int*   ei    = (const int*)d_in[1];
    const float* W1    = (const float*)d_in[2];
    const float* b1    = (const float*)d_in[3];
    const float* W2    = (const float*)d_in[4];
    const float* b2    = (const float*)d_in[5];
    const float* gamma = (const float*)d_in[6];
    const float* beta  = (const float*)d_in[7];
    const float* rm    = (const float*)d_in[8];
    const float* rv    = (const float*)d_in[9];
    float* out = (float*)d_out;

    const int* src = ei;
    const int* dst = ei + E_EDGES;

    // workspace layout
    float*    R     = (float*)d_ws;              // N*64: xw (first half in time), then hw
    float*    agg1  = R + (size_t)N_NODES * 64;  // N*32
    float*    dinv  = agg1 + (size_t)N_NODES * 32; // N
    unsigned* deg   = (unsigned*)(dinv + N_NODES); // N
    float*    scale = (float*)(deg + N_NODES);   // 32
    float*    shift = scale + H_F;               // 32

    hipMemsetAsync(deg, 0, (size_t)N_NODES * sizeof(unsigned), stream);
    hipMemsetAsync(agg1, 0, (size_t)N_NODES * H_F * sizeof(float), stream);

    k_deg<<<(E_EDGES + 255) / 256, 256, 0, stream>>>(dst, deg);
    k_dinv<<<(N_NODES + 255) / 256, 256, 0, stream>>>(deg, dinv);
    k_scales<<<1, 64, 0, stream>>>(gamma, beta, rm, rv, b1, scale, shift);

    // GEMM1: xw (stored in R, stride 32)
    k_gemm1<<<(N_NODES + 7) / 8, 256, 0, stream>>>(x, W1, R);

    // scatter1 over E+N edges, width 32
    {
        long long threads = (long long)ET_EDGES * H_F;
        int blocks = (int)((threads + 255) / 256);
        k_scatter1<<<blocks, 256, 0, stream>>>(src, dst, dinv, R, agg1);
    }

    // GEMM2 (+BN+ReLU): hw stored in R (stride 64, overwrites dead xw)
    k_gemm2<<<(N_NODES + 3) / 4, 256, 0, stream>>>(agg1, W2, scale, shift, R);

    // out = b2, then scatter2 over E+N edges, width 64
    k_init_out<<<(N_NODES * OUT_F + 255) / 256, 256, 0, stream>>>(b2, out);
    {
        long long threads = (long long)ET_EDGES * OUT_F;
        int blocks = (int)((threads + 255) / 256);
        k_scatter2<<<blocks, 256, 0, stream>>>(src, dst, dinv, R, out);
    }
}

// Round 2
// 972.569 us; speedup vs baseline: 1.7319x; 1.7319x over previous
//
#include <hip/hip_runtime.h>

#define N_NODES 100000
#define E_EDGES 3200000
#define IN_F 512
#define H_F 32
#define OUT_F 64
#define BN_EPS 1e-5f

// ---------------- degree ----------------
__global__ void k_deg(const int* __restrict__ dst, unsigned* __restrict__ deg) {
    int i = blockIdx.x * blockDim.x + threadIdx.x;
    if (i < E_EDGES) atomicAdd(&deg[dst[i]], 1u);
}

__global__ void k_dinv(const unsigned* __restrict__ deg, float* __restrict__ dinv) {
    int i = blockIdx.x * blockDim.x + threadIdx.x;
    if (i < N_NODES) dinv[i] = rsqrtf((float)deg[i] + 1.0f);  // +1 self-loop
}

// ---------------- BN fold ----------------
__global__ void k_scales(const float* __restrict__ gamma, const float* __restrict__ beta,
                         const float* __restrict__ rm, const float* __restrict__ rv,
                         const float* __restrict__ b1,
                         float* __restrict__ scale, float* __restrict__ shift) {
    int k = threadIdx.x;
    if (k < H_F) {
        float s = gamma[k] * rsqrtf(rv[k] + BN_EPS);
        scale[k] = s;
        shift[k] = (b1[k] - rm[k]) * s + beta[k];
    }
}

// ---------------- exclusive scan of deg -> off (single block, wave scan) ----------------
__global__ __launch_bounds__(1024) void k_scan(const unsigned* __restrict__ deg,
                                               unsigned* __restrict__ off) {
    __shared__ unsigned wsum[16];
    __shared__ unsigned carry_s;
    int lane = threadIdx.x & 63;
    int wid  = threadIdx.x >> 6;
    if (threadIdx.x == 0) carry_s = 0;
    __syncthreads();
    for (int base = 0; base < N_NODES; base += 1024) {
        int i = base + (int)threadIdx.x;
        unsigned v = (i < N_NODES) ? deg[i] : 0u;
        unsigned x = v;
#pragma unroll
        for (int s = 1; s < 64; s <<= 1) {
            unsigned t = __shfl_up(x, s, 64);
            if (lane >= s) x += t;
        }
        if (lane == 63) wsum[wid] = x;
        __syncthreads();
        unsigned woff = 0, total = 0;
#pragma unroll
        for (int w = 0; w < 16; ++w) {
            unsigned s = wsum[w];
            if (w < wid) woff += s;
            total += s;
        }
        unsigned carry = carry_s;
        if (i < N_NODES) off[i] = carry + woff + x - v;   // exclusive
        __syncthreads();
        if (threadIdx.x == 0) carry_s = carry + total;
        __syncthreads();
    }
    if (threadIdx.x == 0) off[N_NODES] = carry_s;
}

// ---------------- CSR fill ----------------
__global__ void k_fill(const int* __restrict__ src, const int* __restrict__ dst,
                       const unsigned* __restrict__ off, unsigned* __restrict__ cnt,
                       unsigned* __restrict__ csr) {
    int e = blockIdx.x * blockDim.x + threadIdx.x;
    if (e < E_EDGES) {
        int s = src[e], d = dst[e];
        unsigned pos = atomicAdd(&cnt[d], 1u);
        csr[off[d] + pos] = (unsigned)s;
    }
}

// ---------------- GEMM1: xw = (x @ W1) * dinv[row]  ([N,512]x[512,32]) ----------------
// 256 threads, 8 row-groups x 4 rows = 32 rows/block; N = 32*3125 exactly.
__global__ __launch_bounds__(256) void k_gemm1(const float* __restrict__ x,
                                               const float* __restrict__ W1,
                                               const float* __restrict__ dinv,
                                               float* __restrict__ xw) {
    __shared__ float w[IN_F * H_F];  // 64 KB
    for (int i = threadIdx.x; i < IN_F * H_F; i += 256) w[i] = W1[i];
    __syncthreads();
    int c  = threadIdx.x & 31;
    int rg = threadIdx.x >> 5;
    int row0 = blockIdx.x * 32 + rg * 4;
    const float* xp = x + (size_t)row0 * IN_F;
    float a0 = 0.f, a1 = 0.f, a2 = 0.f, a3 = 0.f;
#pragma unroll 4
    for (int k = 0; k < IN_F; k += 4) {
        float4 x0 = *(const float4*)(xp + k);
        float4 x1 = *(const float4*)(xp + IN_F + k);
        float4 x2 = *(const float4*)(xp + 2 * IN_F + k);
        float4 x3 = *(const float4*)(xp + 3 * IN_F + k);
        float w0 = w[(k + 0) * H_F + c];
        float w1 = w[(k + 1) * H_F + c];
        float w2 = w[(k + 2) * H_F + c];
        float w3 = w[(k + 3) * H_F + c];
        a0 = fmaf(x0.x, w0, fmaf(x0.y, w1, fmaf(x0.z, w2, fmaf(x0.w, w3, a0))));
        a1 = fmaf(x1.x, w0, fmaf(x1.y, w1, fmaf(x1.z, w2, fmaf(x1.w, w3, a1))));
        a2 = fmaf(x2.x, w0, fmaf(x2.y, w1, fmaf(x2.z, w2, fmaf(x2.w, w3, a2))));
        a3 = fmaf(x3.x, w0, fmaf(x3.y, w1, fmaf(x3.z, w2, fmaf(x3.w, w3, a3))));
    }
    xw[(size_t)(row0 + 0) * H_F + c] = a0 * dinv[row0 + 0];
    xw[(size_t)(row0 + 1) * H_F + c] = a1 * dinv[row0 + 1];
    xw[(size_t)(row0 + 2) * H_F + c] = a2 * dinv[row0 + 2];
    xw[(size_t)(row0 + 3) * H_F + c] = a3 * dinv[row0 + 3];
}

// ---------------- gather1: hs[d] = relu(bn((sum_in xw[s] + xw[d]) * dinv[d])) * dinv[d] ----------------
// one wave per node; lanes 0-31 / 32-63 process alternating edges.
__global__ __launch_bounds__(256) void k_gather1(const unsigned* __restrict__ off,
                                                 const unsigned* __restrict__ csr,
                                                 const float* __restrict__ xw,
                                                 const float* __restrict__ dinv,
                                                 const float* __restrict__ scale,
                                                 const float* __restrict__ shift,
                                                 float* __restrict__ hs) {
    int wid  = threadIdx.x >> 6;
    int lane = threadIdx.x & 63;
    int c    = lane & 31;
    int half = lane >> 5;
    int d = blockIdx.x * 4 + wid;           // N = 4*25000 exactly
    unsigned beg = off[d], end = off[d + 1];
    float acc = 0.f;
    for (unsigned j = beg + (unsigned)half; j < end; j += 2) {
        unsigned s = csr[j];
        acc += xw[(size_t)s * H_F + c];
    }
    acc += __shfl_xor(acc, 32, 64);
    if (half == 0) {
        float dv = dinv[d];
        float t  = acc + xw[(size_t)d * H_F + c];   // self-loop (xw already has dinv[d])
        float agg = t * dv;
        float h   = fmaxf(fmaf(agg, scale[c], shift[c]), 0.f);
        hs[(size_t)d * H_F + c] = h * dv;
    }
}

// ---------------- gather2: agg2[d] = (sum_in hs[s] + hs[d]) * dinv[d] ----------------
__global__ __launch_bounds__(256) void k_gather2(const unsigned* __restrict__ off,
                                                 const unsigned* __restrict__ csr,
                                                 const float* __restrict__ hs,
                                                 const float* __restrict__ dinv,
                                                 float* __restrict__ agg2) {
    int wid  = threadIdx.x >> 6;
    int lane = threadIdx.x & 63;
    int c    = lane & 31;
    int half = lane >> 5;
    int d = blockIdx.x * 4 + wid;
    unsigned beg = off[d], end = off[d + 1];
    float acc = 0.f;
    for (unsigned j = beg + (unsigned)half; j < end; j += 2) {
        unsigned s = csr[j];
        acc += hs[(size_t)s * H_F + c];
    }
    acc += __shfl_xor(acc, 32, 64);
    if (half == 0) {
        float t = acc + hs[(size_t)d * H_F + c];
        agg2[(size_t)d * H_F + c] = t * dinv[d];
    }
}

// ---------------- gemm_out: out = agg2 @ W2 + b2  ([N,32]x[32,64]) ----------------
__global__ __launch_bounds__(256) void k_gemm_out(const float* __restrict__ agg,
                                                  const float* __restrict__ W2,
                                                  const float* __restrict__ b2,
                                                  float* __restrict__ out) {
    __shared__ float w[H_F * OUT_F];   // 8 KB
    __shared__ float bsh[OUT_F];
    for (int i = threadIdx.x; i < H_F * OUT_F; i += 256) w[i] = W2[i];
    if (threadIdx.x < OUT_F) bsh[threadIdx.x] = b2[threadIdx.x];
    __syncthreads();
    int o = threadIdx.x & 63;
    int r = threadIdx.x >> 6;
    int row = blockIdx.x * 4 + r;            // N = 4*25000 exactly
    const float* ar = agg + (size_t)row * H_F;
    float acc = bsh[o];
#pragma unroll
    for (int k = 0; k < H_F; ++k)
        acc = fmaf(ar[k], w[k * OUT_F + o], acc);
    out[(size_t)row * OUT_F + o] = acc;
}

extern "C" void kernel_launch(void* const* d_in, const int* in_sizes, int n_in,
                              void* d_out, int out_size, void* d_ws, size_t ws_size,
                              hipStream_t stream) {
    const float* x     = (const float*)d_in[0];
    const int*   ei    = (const int*)d_in[1];
    const float* W1    = (const float*)d_in[2];
    const float* b1    = (const float*)d_in[3];
    const float* W2    = (const float*)d_in[4];
    const float* b2    = (const float*)d_in[5];
    const float* gamma = (const float*)d_in[6];
    const float* beta  = (const float*)d_in[7];
    const float* rm    = (const float*)d_in[8];
    const float* rv    = (const float*)d_in[9];
    float* out = (float*)d_out;

    const int* src = ei;
    const int* dst = ei + E_EDGES;

    // workspace layout
    float*    xw    = (float*)d_ws;                  // N*32
    float*    hs    = xw + (size_t)N_NODES * H_F;    // N*32
    float*    agg2  = xw;                            // alias: xw dead after gather1
    float*    dinv  = hs + (size_t)N_NODES * H_F;    // N
    unsigned* deg   = (unsigned*)(dinv + N_NODES);   // N
    unsigned* cnt   = deg + N_NODES;                 // N
    unsigned* off   = cnt + N_NODES;                 // N+1
    unsigned* csr   = off + N_NODES + 1;             // E
    float*    scale = (float*)(csr + E_EDGES);       // 32
    float*    shift = scale + H_F;                   // 32

    hipMemsetAsync(deg, 0, (size_t)N_NODES * sizeof(unsigned), stream);
    hipMemsetAsync(cnt, 0, (size_t)N_NODES * sizeof(unsigned), stream);

    k_deg<<<(E_EDGES + 255) / 256, 256, 0, stream>>>(dst, deg);
    k_dinv<<<(N_NODES + 255) / 256, 256, 0, stream>>>(deg, dinv);
    k_scales<<<1, 64, 0, stream>>>(gamma, beta, rm, rv, b1, scale, shift);
    k_scan<<<1, 1024, 0, stream>>>(deg, off);
    k_fill<<<(E_EDGES + 255) / 256, 256, 0, stream>>>(src, dst, off, cnt, csr);

    k_gemm1<<<N_NODES / 32, 256, 0, stream>>>(x, W1, dinv, xw);
    k_gather1<<<N_NODES / 4, 256, 0, stream>>>(off, csr, xw, dinv, scale, shift, hs);
    k_gather2<<<N_NODES / 4, 256, 0, stream>>>(off, csr, hs, dinv, agg2);
    k_gemm_out<<<N_NODES / 4, 256, 0, stream>>>(agg2, W2, b2, out);
}

// Round 3
// 542.403 us; speedup vs baseline: 3.1054x; 1.7931x over previous
//
#include <hip/hip_runtime.h>

#define N_NODES 100000
#define E_EDGES 3200000
#define IN_F 512
#define H_F 32
#define OUT_F 64
#define BN_EPS 1e-5f

// ---------------- degree ----------------
__global__ void k_deg(const int* __restrict__ dst, unsigned* __restrict__ deg) {
    int i = blockIdx.x * blockDim.x + threadIdx.x;
    if (i < E_EDGES) atomicAdd(&deg[dst[i]], 1u);
}

// ---------------- offsets (unordered buckets) + dinv, fused ----------------
__global__ __launch_bounds__(256) void k_off(const unsigned* __restrict__ deg,
                                             unsigned* __restrict__ off,
                                             float* __restrict__ dinv,
                                             unsigned* __restrict__ counter) {
    __shared__ unsigned wtot[4];
    __shared__ unsigned bbase;
    int i = blockIdx.x * 256 + threadIdx.x;
    int lane = threadIdx.x & 63;
    int wid  = threadIdx.x >> 6;
    unsigned v = (i < N_NODES) ? deg[i] : 0u;
    if (i < N_NODES) dinv[i] = rsqrtf((float)v + 1.0f);   // +1 self-loop
    unsigned xs = v;
#pragma unroll
    for (int s = 1; s < 64; s <<= 1) {
        unsigned t = __shfl_up(xs, s, 64);
        if (lane >= s) xs += t;
    }
    if (lane == 63) wtot[wid] = xs;
    __syncthreads();
    if (threadIdx.x == 0)
        bbase = atomicAdd(counter, wtot[0] + wtot[1] + wtot[2] + wtot[3]);
    __syncthreads();
    unsigned wbase = 0;
#pragma unroll
    for (int w = 0; w < 4; ++w) if (w < wid) wbase += wtot[w];
    if (i < N_NODES) off[i] = bbase + wbase + xs - v;     // exclusive within block
}

// ---------------- BN fold ----------------
__global__ void k_scales(const float* __restrict__ gamma, const float* __restrict__ beta,
                         const float* __restrict__ rm, const float* __restrict__ rv,
                         const float* __restrict__ b1,
                         float* __restrict__ scale, float* __restrict__ shift) {
    int k = threadIdx.x;
    if (k < H_F) {
        float s = gamma[k] * rsqrtf(rv[k] + BN_EPS);
        scale[k] = s;
        shift[k] = (b1[k] - rm[k]) * s + beta[k];
    }
}

// ---------------- CSR fill ----------------
__global__ void k_fill(const int* __restrict__ src, const int* __restrict__ dst,
                       const unsigned* __restrict__ off, unsigned* __restrict__ cnt,
                       unsigned* __restrict__ csr) {
    int e = blockIdx.x * blockDim.x + threadIdx.x;
    if (e < E_EDGES) {
        int s = src[e], d = dst[e];
        unsigned pos = atomicAdd(&cnt[d], 1u);
        csr[off[d] + pos] = (unsigned)s;
    }
}

// ---------------- GEMM1: xw = (x @ W1) * dinv[row]  ([N,512]x[512,32]) ----------------
// 128-row x 32-k LDS tiles, XOR-swizzled x tile; thread computes 4 rows x 4 cols.
#define TM 128
#define TK 32
__global__ __launch_bounds__(256) void k_gemm1(const float* __restrict__ x,
                                               const float* __restrict__ W1,
                                               const float* __restrict__ dinv,
                                               float* __restrict__ xw) {
    __shared__ float xs[TM * TK];   // 16 KB, quad-swizzled: (r,k) -> r*32 + ((k>>2 ^ (r&7))<<2) + (k&3)
    __shared__ float ws[TK * H_F];  // 4 KB
    const int t   = threadIdx.x;
    const int tr  = t >> 3;         // 0..31
    const int tq  = t & 7;          // 0..7
    const int c0  = tq * 4;
    const int swz = tr & 7;
    const int row0 = blockIdx.x * TM;
    float acc[4][4] = {};
    for (int k0 = 0; k0 < IN_F; k0 += TK) {
        // stage x tile: 4 passes of 32 rows, 8 lanes x float4 per row
#pragma unroll
        for (int p = 0; p < 4; ++p) {
            int r = p * 32 + tr;
            int gr = row0 + r;
            if (gr >= N_NODES) gr = N_NODES - 1;
            float4 v = *(const float4*)(x + (size_t)gr * IN_F + k0 + tq * 4);
            *(float4*)&xs[r * TK + ((tq ^ (r & 7)) << 2)] = v;
        }
        // stage w tile: 32x32
        {
            float4 v = *(const float4*)(W1 + (size_t)(k0 + tr) * H_F + tq * 4);
            *(float4*)&ws[tr * H_F + tq * 4] = v;
        }
        __syncthreads();
#pragma unroll
        for (int kk = 0; kk < TK; kk += 4) {
            float xr[4][4], wr[4][4];
            const int q = ((kk >> 2) ^ swz) << 2;
#pragma unroll
            for (int i = 0; i < 4; ++i) {
                float4 v = *(const float4*)&xs[(tr + 32 * i) * TK + q];
                xr[i][0] = v.x; xr[i][1] = v.y; xr[i][2] = v.z; xr[i][3] = v.w;
            }
#pragma unroll
            for (int j = 0; j < 4; ++j) {
                float4 v = *(const float4*)&ws[(kk + j) * H_F + c0];
                wr[j][0] = v.x; wr[j][1] = v.y; wr[j][2] = v.z; wr[j][3] = v.w;
            }
#pragma unroll
            for (int k = 0; k < 4; ++k)
#pragma unroll
                for (int i = 0; i < 4; ++i)
#pragma unroll
                    for (int j = 0; j < 4; ++j)
                        acc[i][j] = fmaf(xr[i][k], wr[k][j], acc[i][j]);
        }
        __syncthreads();
    }
#pragma unroll
    for (int i = 0; i < 4; ++i) {
        int r = row0 + tr + 32 * i;
        if (r < N_NODES) {
            float dv = dinv[r];
            float4 o = make_float4(acc[i][0] * dv, acc[i][1] * dv, acc[i][2] * dv, acc[i][3] * dv);
            *(float4*)(xw + (size_t)r * H_F + c0) = o;
        }
    }
}

// ---------------- gather1: hs[d] = relu(bn((sum_in xw[s] + xw[d]) * dinv[d])) * dinv[d] ----------------
// one wave per node: 8 edge-groups x 8 lanes x float4 (8 rows in flight)
__global__ __launch_bounds__(256) void k_gather1(const unsigned* __restrict__ off,
                                                 const unsigned* __restrict__ deg,
                                                 const unsigned* __restrict__ csr,
                                                 const float* __restrict__ xw,
                                                 const float* __restrict__ dinv,
                                                 const float* __restrict__ scale,
                                                 const float* __restrict__ shift,
                                                 float* __restrict__ hs) {
    int wid  = threadIdx.x >> 6;
    int lane = threadIdx.x & 63;
    int g    = lane >> 3;
    int q    = lane & 7;
    int d = blockIdx.x * 4 + wid;                    // N = 4*25000 exactly
    unsigned beg = off[d];
    unsigned end = beg + deg[d];
    float4 acc = make_float4(0.f, 0.f, 0.f, 0.f);
    for (unsigned j = beg + (unsigned)g; j < end; j += 8) {
        unsigned s = csr[j];
        float4 v = *(const float4*)(xw + (size_t)s * H_F + q * 4);
        acc.x += v.x; acc.y += v.y; acc.z += v.z; acc.w += v.w;
    }
#pragma unroll
    for (int st = 8; st < 64; st <<= 1) {
        acc.x += __shfl_xor(acc.x, st, 64);
        acc.y += __shfl_xor(acc.y, st, 64);
        acc.z += __shfl_xor(acc.z, st, 64);
        acc.w += __shfl_xor(acc.w, st, 64);
    }
    if (g == 0) {
        float dv = dinv[d];
        float4 sv = *(const float4*)(xw + (size_t)d * H_F + q * 4);   // self-loop
        float4 sc = *(const float4*)(scale + q * 4);
        float4 sh = *(const float4*)(shift + q * 4);
        float4 h;
        h.x = fmaxf(fmaf((acc.x + sv.x) * dv, sc.x, sh.x), 0.f) * dv;
        h.y = fmaxf(fmaf((acc.y + sv.y) * dv, sc.y, sh.y), 0.f) * dv;
        h.z = fmaxf(fmaf((acc.z + sv.z) * dv, sc.z, sh.z), 0.f) * dv;
        h.w = fmaxf(fmaf((acc.w + sv.w) * dv, sc.w, sh.w), 0.f) * dv;
        *(float4*)(hs + (size_t)d * H_F + q * 4) = h;
    }
}

// ---------------- gather2 + out-GEMM fused: out[d] = ((sum_in hs[s] + hs[d])*dinv[d]) @ W2 + b2 ----------------
__global__ __launch_bounds__(256) void k_gather2(const unsigned* __restrict__ off,
                                                 const unsigned* __restrict__ deg,
                                                 const unsigned* __restrict__ csr,
                                                 const float* __restrict__ hs,
                                                 const float* __restrict__ dinv,
                                                 const float* __restrict__ W2,
                                                 const float* __restrict__ b2,
                                                 float* __restrict__ out) {
    __shared__ float ws[H_F * OUT_F];   // 8 KB
    __shared__ float bs[OUT_F];
    for (int i = threadIdx.x; i < H_F * OUT_F; i += 256) ws[i] = W2[i];
    if (threadIdx.x < OUT_F) bs[threadIdx.x] = b2[threadIdx.x];
    __syncthreads();
    int wid  = threadIdx.x >> 6;
    int lane = threadIdx.x & 63;
    int g    = lane >> 3;
    int q    = lane & 7;
    int d = blockIdx.x * 4 + wid;
    unsigned beg = off[d];
    unsigned end = beg + deg[d];
    float4 acc = make_float4(0.f, 0.f, 0.f, 0.f);
    for (unsigned j = beg + (unsigned)g; j < end; j += 8) {
        unsigned s = csr[j];
        float4 v = *(const float4*)(hs + (size_t)s * H_F + q * 4);
        acc.x += v.x; acc.y += v.y; acc.z += v.z; acc.w += v.w;
    }
#pragma unroll
    for (int st = 8; st < 64; st <<= 1) {
        acc.x += __shfl_xor(acc.x, st, 64);
        acc.y += __shfl_xor(acc.y, st, 64);
        acc.z += __shfl_xor(acc.z, st, 64);
        acc.w += __shfl_xor(acc.w, st, 64);
    }
    // every lane now holds the group-reduced sums for cols q*4..q*4+3
    float dv = dinv[d];
    float4 sv = *(const float4*)(hs + (size_t)d * H_F + q * 4);       // self-loop
    float tv[4];
    tv[0] = (acc.x + sv.x) * dv;
    tv[1] = (acc.y + sv.y) * dv;
    tv[2] = (acc.z + sv.z) * dv;
    tv[3] = (acc.w + sv.w) * dv;
    // out[d][lane] = b2[lane] + sum_k agg[k] * W2[k][lane]
    float o = bs[lane];
#pragma unroll
    for (int k = 0; k < H_F; ++k) {
        float a = __shfl(tv[k & 3], k >> 2, 8);   // agg[k] from the lane owning quad k>>2
        o = fmaf(a, ws[k * OUT_F + lane], o);
    }
    out[(size_t)d * OUT_F + lane] = o;
}

extern "C" void kernel_launch(void* const* d_in, const int* in_sizes, int n_in,
                              void* d_out, int out_size, void* d_ws, size_t ws_size,
                              hipStream_t stream) {
    const float* x     = (const float*)d_in[0];
    const int*   ei    = (const int*)d_in[1];
    const float* W1    = (const float*)d_in[2];
    const float* b1    = (const float*)d_in[3];
    const float* W2    = (const float*)d_in[4];
    const float* b2    = (const float*)d_in[5];
    const float* gamma = (const float*)d_in[6];
    const float* beta  = (const float*)d_in[7];
    const float* rm    = (const float*)d_in[8];
    const float* rv    = (const float*)d_in[9];
    float* out = (float*)d_out;

    const int* src = ei;
    const int* dst = ei + E_EDGES;

    // workspace layout
    float*    xw      = (float*)d_ws;                  // N*32
    float*    hs      = xw + (size_t)N_NODES * H_F;    // N*32
    float*    dinv    = hs + (size_t)N_NODES * H_F;    // N
    float*    scale   = dinv + N_NODES;                // 32
    float*    shift   = scale + H_F;                   // 32
    unsigned* deg     = (unsigned*)(shift + H_F);      // N
    unsigned* cnt     = deg + N_NODES;                 // N
    unsigned* off     = cnt + N_NODES;                 // N
    unsigned* counter = off + N_NODES;                 // 1
    unsigned* csr     = counter + 1;                   // E

    hipMemsetAsync(deg, 0, (size_t)N_NODES * sizeof(unsigned), stream);
    hipMemsetAsync(cnt, 0, (size_t)N_NODES * sizeof(unsigned), stream);
    hipMemsetAsync(counter, 0, sizeof(unsigned), stream);

    k_deg<<<(E_EDGES + 255) / 256, 256, 0, stream>>>(dst, deg);
    k_off<<<(N_NODES + 255) / 256, 256, 0, stream>>>(deg, off, dinv, counter);
    k_scales<<<1, 64, 0, stream>>>(gamma, beta, rm, rv, b1, scale, shift);
    k_fill<<<(E_EDGES + 255) / 256, 256, 0, stream>>>(src, dst, off, cnt, csr);

    k_gemm1<<<(N_NODES + TM - 1) / TM, 256, 0, stream>>>(x, W1, dinv, xw);
    k_gather1<<<N_NODES / 4, 256, 0, stream>>>(off, deg, csr, xw, dinv, scale, shift, hs);
    k_gather2<<<N_NODES / 4, 256, 0, stream>>>(off, deg, csr, hs, dinv, W2, b2, out);
}